// Round 3
// baseline (1012.644 us; speedup 1.0000x reference)
//
#include <hip/hip_runtime.h>
#include <hip/hip_bf16.h>

#define C_DIM 256
#define HW_DIM 16384
#define F_DIM 1024

typedef __hip_bfloat16 bf16;
typedef short short8 __attribute__((ext_vector_type(8)));
typedef float f32x4 __attribute__((ext_vector_type(4)));

__device__ __forceinline__ float bf2f(unsigned short u) {
  unsigned int x = ((unsigned int)u) << 16;
  return __uint_as_float(x);
}
__device__ __forceinline__ unsigned short f2bfbits(float v) {
  bf16 h = __float2bfloat16(v);
  return *(unsigned short*)&h;
}

// Fragment layout used for X and XA (per window):
//   FR(win, mt, ks, l, j) at ((((win*16)+mt)*8+ks)*64+l)*8+j
//   = X[c = ks*32 + (l>>4)*8 + j][token n = mt*16 + (l&15)]
// This is exactly the MFMA B-fragment order: a wave's 64 lanes reading
// (mt, ks) get their short8 as one contiguous 1 KiB block.

// ---------------- kernel 0: weight prep ----------------
__global__ __launch_bounds__(256) void prep_weights(
    const float* __restrict__ Wq, const float* __restrict__ Wk,
    const float* __restrict__ Wv, const float* __restrict__ W1,
    const float* __restrict__ W2, unsigned short* __restrict__ Wqkv,
    unsigned short* __restrict__ W1s, unsigned short* __restrict__ W2s) {
  int i = blockIdx.x * 256 + threadIdx.x;
  if (i < 320 * 256) {
    int r = i >> 8, c = i & 255;
    float v;
    if (r < 32)      v = Wq[r * 256 + c];
    else if (r < 64) v = Wk[(r - 32) * 256 + c];
    else             v = Wv[(r - 64) * 256 + c];
    Wqkv[i] = f2bfbits(v);
  }
  if (i < 32768) {
    int ft = i >> 9, ks = (i >> 6) & 7, l = i & 63;
    int f = ft * 16 + (l & 15), kb = ks * 32 + (l >> 4) * 8;
    #pragma unroll
    for (int j = 0; j < 8; ++j)
      W1s[i * 8 + j] = f2bfbits(W1[f * 256 + kb + j]);
  }
  if (i < 32768) {
    int ct = i >> 11, gks = (i >> 6) & 31, l = i & 63;
    int c = ct * 16 + (l & 15), fb = gks * 32 + (l >> 4) * 8;
    #pragma unroll
    for (int j = 0; j < 8; ++j)
      W2s[i * 8 + j] = f2bfbits(W2[c * 1024 + fb + j]);
  }
}

// ---------------- kernel 0b: x -> Xfrag (fragment-order bf16 transpose) ----------------
// thread = one (win, mt, ks, lane): 8 scalar f32 loads (64-B coalesced groups),
// one contiguous 16-B store. Memory-bound: 128 MB read + 64 MB write.
__global__ __launch_bounds__(256) void xprep_kernel(
    const float* __restrict__ x, unsigned short* __restrict__ Xfrag) {
  const int gtid = blockIdx.x * 256 + threadIdx.x;   // [0, 4194304)
  const int win = gtid >> 13;
  const int rem = gtid & 8191;
  const int mt = rem >> 9, ks = (rem >> 6) & 7, l = rem & 63;
  const int t = l & 15, q = l >> 4;
  const int b = win >> 6, wh = (win >> 3) & 7, ww = win & 7;
  const int h = wh * 16 + mt, w = ww * 16 + t;
  const int c0 = ks * 32 + q * 8;
  const float* xp = x + ((size_t)(b * 256 + c0) * 128 + h) * 128 + w;
  short8 v;
  #pragma unroll
  for (int j = 0; j < 8; ++j)
    v[j] = (short)f2bfbits(xp[(size_t)j * 16384]);
  *(short8*)(Xfrag + (size_t)gtid * 8) = v;
}

// ---------------- kernel 1: QKV projection (LDS-free, barrier-free) ----------------
// block = (win, mc). B-fragments are contiguous b128 loads from Xfrag.
// Qw/Kw [win][token 256][32] bf16;  Vw [win][c 256][m 256] bf16.
__global__ __launch_bounds__(256) void qkvproj_kernel(
    const unsigned short* __restrict__ Xfrag, const unsigned short* __restrict__ Wqkv,
    unsigned short* __restrict__ Qw, unsigned short* __restrict__ Kw,
    unsigned short* __restrict__ Vw) {
  const int bid = blockIdx.x;
  const int win = bid >> 2, mc = bid & 3;
  const int m0 = mc * 64;
  const int tid = threadIdx.x;
  const int wv = tid >> 6, l = tid & 63;
  const int t = l & 15, q = l >> 4;
  const unsigned short* Xb = Xfrag + (size_t)win * 65536;

  for (int mt = 0; mt < 4; ++mt) {
    short8 Bf[8];
    #pragma unroll
    for (int ks = 0; ks < 8; ++ks)
      Bf[ks] = *(const short8*)(Xb + (((size_t)(mc * 4 + mt) * 8 + ks) * 64 + l) * 8);
    #pragma unroll
    for (int rti = 0; rti < 5; ++rti) {
      const int rt = wv * 5 + rti;
      const int r0 = rt * 16;
      f32x4 acc = (f32x4){0.f, 0.f, 0.f, 0.f};
      #pragma unroll
      for (int ks = 0; ks < 8; ++ks) {
        short8 av = *(const short8*)(Wqkv + (size_t)(r0 + t) * 256 + ks * 32 + q * 8);
        acc = __builtin_amdgcn_mfma_f32_16x16x32_bf16(av, Bf[ks], acc, 0, 0, 0);
      }
      const int n = m0 + mt * 16 + t;   // token
      if (rt < 4) {
        ushort4 u;
        u.x = f2bfbits(acc[0]); u.y = f2bfbits(acc[1]);
        u.z = f2bfbits(acc[2]); u.w = f2bfbits(acc[3]);
        unsigned short* dst = (rt < 2) ? Qw : Kw;
        int o0 = (rt & 1) * 16 + q * 4;
        *(ushort4*)(dst + ((size_t)win * 256 + n) * 32 + o0) = u;
      } else {
        #pragma unroll
        for (int r = 0; r < 4; ++r) {
          int c = r0 - 64 + q * 4 + r;
          Vw[((size_t)win * 256 + c) * 256 + n] = f2bfbits(acc[r]);
        }
      }
    }
  }
}

// ---------------- kernel 2: fused window attention ----------------
// 1 block/window, 1024 thr = 16 waves. S = Q K^T -> exp -> Ps (LDS bf16) ->
// O^T += V P^T (swapped operands: lane holds 4 consecutive channels per token).
// Epilogue: residual from Xfrag (8-B bf16 loads), output to XAfrag in
// fragment order (8-B stores) so ffn needs no staging.
__global__ __launch_bounds__(1024) void attn_fused_kernel(
    const unsigned short* __restrict__ Qw, const unsigned short* __restrict__ Kw,
    const unsigned short* __restrict__ Vw, const unsigned short* __restrict__ Xfrag,
    const float* __restrict__ gamma, unsigned short* __restrict__ XAfrag) {
  __shared__ __align__(16) short Ps[256][72];  // 36864 B
  __shared__ float Lpart[4][4][64];
  __shared__ float Ls[256];

  const int win = blockIdx.x;
  const int tid = threadIdx.x;
  const int wid = tid >> 6, l = tid & 63;
  const int t = l & 15, q = l >> 4;
  const int wr = wid >> 2, wc = wid & 3;

  f32x4 Oacc[4][4];   // [k: c-tile][i: n-tile]
  #pragma unroll
  for (int k = 0; k < 4; ++k)
    #pragma unroll
    for (int i = 0; i < 4; ++i)
      Oacc[k][i] = (f32x4){0.f, 0.f, 0.f, 0.f};
  float lsum[16];
  #pragma unroll
  for (int e = 0; e < 16; ++e) lsum[e] = 0.f;

  const unsigned short* Qb = Qw + (size_t)win * 256 * 32;
  const unsigned short* Kb = Kw + (size_t)win * 256 * 32;
  const unsigned short* Vb = Vw + (size_t)win * 65536;

  short8 aq[4];
  #pragma unroll
  for (int i = 0; i < 4; ++i)
    aq[i] = *(const short8*)(Qb + (size_t)((wr * 4 + i) * 16 + t) * 32 + q * 8);

  for (int mcc = 0; mcc < 4; ++mcc) {
    // ---- S chunk ----
    {
      const int m0s = (mcc * 4 + wc) * 16;
      short8 bk = *(const short8*)(Kb + (size_t)(m0s + t) * 32 + q * 8);
      f32x4 sv[4];
      #pragma unroll
      for (int i = 0; i < 4; ++i)
        sv[i] = __builtin_amdgcn_mfma_f32_16x16x32_bf16(aq[i], bk, (f32x4){0.f,0.f,0.f,0.f}, 0, 0, 0);
      #pragma unroll
      for (int i = 0; i < 4; ++i) {
        #pragma unroll
        for (int r = 0; r < 4; ++r) {
          float e = __expf(sv[i][r]);
          lsum[i * 4 + r] += e;
          Ps[(wr * 4 + i) * 16 + q * 4 + r][wc * 16 + t] = (short)f2bfbits(e);
        }
      }
    }
    __syncthreads();
    // ---- PV chunk (swapped) ----
    #pragma unroll
    for (int ks2 = 0; ks2 < 2; ++ks2) {
      short8 ap[4], bv[4];
      #pragma unroll
      for (int i = 0; i < 4; ++i)
        ap[i] = *(const short8*)&Ps[(wr * 4 + i) * 16 + t][ks2 * 32 + q * 8];
      #pragma unroll
      for (int k = 0; k < 4; ++k)
        bv[k] = *(const short8*)(Vb + (size_t)((wc * 4 + k) * 16 + t) * 256 + mcc * 64 + ks2 * 32 + q * 8);
      #pragma unroll
      for (int k = 0; k < 4; ++k)
        #pragma unroll
        for (int i = 0; i < 4; ++i)
          Oacc[k][i] = __builtin_amdgcn_mfma_f32_16x16x32_bf16(bv[k], ap[i], Oacc[k][i], 0, 0, 0);
    }
    __syncthreads();
  }

  // ---- row sums ----
  #pragma unroll
  for (int mask = 1; mask < 16; mask <<= 1)
    #pragma unroll
    for (int e = 0; e < 16; ++e)
      lsum[e] += __shfl_xor(lsum[e], mask);
  if (t == 0) {
    #pragma unroll
    for (int i = 0; i < 4; ++i)
      *(float4*)&Lpart[wr][wc][i * 16 + q * 4] =
          make_float4(lsum[i * 4 + 0], lsum[i * 4 + 1], lsum[i * 4 + 2], lsum[i * 4 + 3]);
  }
  __syncthreads();
  if (tid < 256) {
    int wrr = tid >> 6, nl = tid & 63;
    float s = Lpart[wrr][0][nl] + Lpart[wrr][1][nl] + Lpart[wrr][2][nl] + Lpart[wrr][3][nl];
    Ls[tid] = gamma[0] / s;
  }
  __syncthreads();

  // ---- epilogue: frag-order residual + frag-order store ----
  const unsigned short* Xres = Xfrag + (size_t)win * 65536;
  unsigned short* XAb = XAfrag + (size_t)win * 65536;
  #pragma unroll
  for (int i = 0; i < 4; ++i) {
    const int n = (wr * 4 + i) * 16 + t;
    const float ls = Ls[n];
    #pragma unroll
    for (int k = 0; k < 4; ++k) {
      // c-range = (wc*4+k)*16 + q*4 .. +3  ->  frag coords
      const size_t off = (((size_t)(wr * 4 + i) * 8 + wc * 2 + (k >> 1)) * 64 +
                          ((k & 1) * 2 + (q >> 1)) * 16 + t) * 8 + (q & 1) * 4;
      ushort4 xa4 = *(const ushort4*)(Xres + off);
      const unsigned short* xp = (const unsigned short*)&xa4;
      ushort4 u;
      unsigned short* up = (unsigned short*)&u;
      #pragma unroll
      for (int r = 0; r < 4; ++r)
        up[r] = f2bfbits(ls * Oacc[k][i][r] + bf2f(xp[r]));
      *(ushort4*)(XAb + off) = u;
    }
  }
}

// ---------------- kernel 3: fused MFMA FFN + both LayerNorms ----------------
// block = (win, mc): 64 pixels. H-GEMM B-frags are contiguous b128 loads
// straight from XAfrag (L1/L2-resident 32 KB/block) — no Xt LDS, no staging
// barrier. LDS = Ht + red = 19456 B -> occupancy capped by VGPR only.
__global__ __launch_bounds__(256, 4) void ffn_mfma_kernel(
    const unsigned short* __restrict__ XAfrag,
    const unsigned short* __restrict__ W1s, const unsigned short* __restrict__ W2s,
    const float* __restrict__ b1, const float* __restrict__ b2,
    const float* __restrict__ ln1w, const float* __restrict__ ln1b,
    const float* __restrict__ ln2w, const float* __restrict__ ln2b,
    float* __restrict__ out) {
  __shared__ __align__(16) short Ht[64][136];     // 17408 B
  __shared__ float red[2][4][64];                 // 2048 B

  const int bid = blockIdx.x;
  const int win = bid >> 2, mc = bid & 3;
  const int b = win >> 6, wh = (win >> 3) & 7, ww = win & 7;
  const int tid = threadIdx.x;
  const int wv = tid >> 6, l = tid & 63;
  const int p = l & 15, q = l >> 4;
  const unsigned short* XAb = XAfrag + (size_t)win * 65536;

  f32x4 Yacc[4][4];
  #pragma unroll
  for (int i = 0; i < 4; ++i)
    #pragma unroll
    for (int pt = 0; pt < 4; ++pt)
      Yacc[i][pt] = (f32x4){0.f, 0.f, 0.f, 0.f};

  const short8* W1s8 = (const short8*)W1s;
  const short8* W2s8 = (const short8*)W2s;

  for (int fc = 0; fc < 8; ++fc) {
    f32x4 Hacc[2][4];
    #pragma unroll
    for (int i = 0; i < 2; ++i)
      #pragma unroll
      for (int pt = 0; pt < 4; ++pt)
        Hacc[i][pt] = (f32x4){0.f, 0.f, 0.f, 0.f};
    const int f0 = (fc * 8 + wv * 2) * 8;
    #pragma unroll
    for (int ks = 0; ks < 8; ++ks) {
      short8 a0 = W1s8[(f0 + ks) * 64 + l];
      short8 a1 = W1s8[(f0 + 8 + ks) * 64 + l];
      #pragma unroll
      for (int pt = 0; pt < 4; ++pt) {
        short8 bf = *(const short8*)(XAb + (((size_t)(mc * 4 + pt) * 8 + ks) * 64 + l) * 8);
        Hacc[0][pt] = __builtin_amdgcn_mfma_f32_16x16x32_bf16(a0, bf, Hacc[0][pt], 0, 0, 0);
        Hacc[1][pt] = __builtin_amdgcn_mfma_f32_16x16x32_bf16(a1, bf, Hacc[1][pt], 0, 0, 0);
      }
    }
    __syncthreads();   // all waves finished reading Ht (previous fc's Y-GEMM)
    // bias + GELU -> Ht
    #pragma unroll
    for (int i = 0; i < 2; ++i) {
      float4 bv1 = *(const float4*)(b1 + fc * 128 + wv * 32 + i * 16 + q * 4);
      #pragma unroll
      for (int pt = 0; pt < 4; ++pt) {
        ushort4 hbv;
        unsigned short* hp = (unsigned short*)&hbv;
        #pragma unroll
        for (int r = 0; r < 4; ++r) {
          float v = Hacc[i][pt][r] + ((const float*)&bv1)[r];
          float u = 0.7978845608f * fmaf(0.044715f * v, v * v, v);
          float e = __expf(2.f * u);
          float g = v - v / (e + 1.f);
          hp[r] = f2bfbits(g);
        }
        *(ushort4*)&Ht[pt * 16 + p][wv * 32 + i * 16 + q * 4] = hbv;
      }
    }
    __syncthreads();   // Ht ready
    #pragma unroll
    for (int fs = 0; fs < 4; ++fs) {
      short8 av[4];
      #pragma unroll
      for (int i = 0; i < 4; ++i)
        av[i] = W2s8[((wv * 4 + i) * 32 + fc * 4 + fs) * 64 + l];
      #pragma unroll
      for (int pt = 0; pt < 4; ++pt) {
        short8 bf = *(const short8*)&Ht[pt * 16 + p][fs * 32 + q * 8];
        #pragma unroll
        for (int i = 0; i < 4; ++i)
          Yacc[i][pt] = __builtin_amdgcn_mfma_f32_16x16x32_bf16(av[i], bf, Yacc[i][pt], 0, 0, 0);
      }
    }
  }

  // bias b2
  #pragma unroll
  for (int i = 0; i < 4; ++i) {
    float4 bb = *(const float4*)(b2 + wv * 64 + i * 16 + q * 4);
    #pragma unroll
    for (int pt = 0; pt < 4; ++pt)
      #pragma unroll
      for (int r = 0; r < 4; ++r)
        Yacc[i][pt][r] += ((const float*)&bb)[r];
  }

  // LN1 stats
  #pragma unroll
  for (int pt = 0; pt < 4; ++pt) {
    float ss = 0.f, sq = 0.f;
    #pragma unroll
    for (int i = 0; i < 4; ++i)
      #pragma unroll
      for (int r = 0; r < 4; ++r) { float v = Yacc[i][pt][r]; ss += v; sq += v * v; }
    ss += __shfl_xor(ss, 16); sq += __shfl_xor(sq, 16);
    ss += __shfl_xor(ss, 32); sq += __shfl_xor(sq, 32);
    if (l < 16) { red[0][wv][pt * 16 + l] = ss; red[1][wv][pt * 16 + l] = sq; }
  }
  __syncthreads();
  if (tid < 64) {
    float S  = red[0][0][tid] + red[0][1][tid] + red[0][2][tid] + red[0][3][tid];
    float Q2 = red[1][0][tid] + red[1][1][tid] + red[1][2][tid] + red[1][3][tid];
    float m = S * 0.00390625f;
    float va = Q2 * 0.00390625f - m * m;
    red[0][0][tid] = m; red[1][0][tid] = rsqrtf(va + 1e-5f);
  }
  __syncthreads();
  // x2 = xa + LN1(y); xa re-read from XAfrag (global, frag-order 8-B loads)
  #pragma unroll
  for (int i = 0; i < 4; ++i) {
    float4 w1v = *(const float4*)(ln1w + wv * 64 + i * 16 + q * 4);
    float4 b1v = *(const float4*)(ln1b + wv * 64 + i * 16 + q * 4);
    #pragma unroll
    for (int pt = 0; pt < 4; ++pt) {
      int px = pt * 16 + p;
      float mu = red[0][0][px], rs = red[1][0][px];
      const size_t off = (((size_t)(mc * 4 + pt) * 8 + wv * 2 + (i >> 1)) * 64 +
                          ((i & 1) * 2 + (q >> 1)) * 16 + p) * 8 + (q & 1) * 4;
      ushort4 xa4 = *(const ushort4*)(XAb + off);
      const unsigned short* xp = (const unsigned short*)&xa4;
      #pragma unroll
      for (int r = 0; r < 4; ++r)
        Yacc[i][pt][r] = bf2f(xp[r]) + (Yacc[i][pt][r] - mu) * rs * ((const float*)&w1v)[r] + ((const float*)&b1v)[r];
    }
  }
  __syncthreads();   // protect red[*][0][*] before stats-2 overwrites
  // LN2 stats
  #pragma unroll
  for (int pt = 0; pt < 4; ++pt) {
    float ss = 0.f, sq = 0.f;
    #pragma unroll
    for (int i = 0; i < 4; ++i)
      #pragma unroll
      for (int r = 0; r < 4; ++r) { float v = Yacc[i][pt][r]; ss += v; sq += v * v; }
    ss += __shfl_xor(ss, 16); sq += __shfl_xor(sq, 16);
    ss += __shfl_xor(ss, 32); sq += __shfl_xor(sq, 32);
    if (l < 16) { red[0][wv][pt * 16 + l] = ss; red[1][wv][pt * 16 + l] = sq; }
  }
  __syncthreads();
  if (tid < 64) {
    float S  = red[0][0][tid] + red[0][1][tid] + red[0][2][tid] + red[0][3][tid];
    float Q2 = red[1][0][tid] + red[1][1][tid] + red[1][2][tid] + red[1][3][tid];
    float m = S * 0.00390625f;
    float va = Q2 * 0.00390625f - m * m;
    red[0][0][tid] = m; red[1][0][tid] = rsqrtf(va + 1e-5f);
  }
  __syncthreads();
  // out = x2 + LN2(x2), NCHW
  #pragma unroll
  for (int i = 0; i < 4; ++i) {
    float4 w2v = *(const float4*)(ln2w + wv * 64 + i * 16 + q * 4);
    float4 b2v = *(const float4*)(ln2b + wv * 64 + i * 16 + q * 4);
    #pragma unroll
    for (int pt = 0; pt < 4; ++pt) {
      int px = pt * 16 + p;
      float mu = red[0][0][px], rs = red[1][0][px];
      #pragma unroll
      for (int r = 0; r < 4; ++r) {
        int c = wv * 64 + i * 16 + q * 4 + r;
        float x2 = Yacc[i][pt][r];
        float o = x2 + (x2 - mu) * rs * ((const float*)&w2v)[r] + ((const float*)&b2v)[r];
        out[(((size_t)(b * 256 + c) * 128) + wh * 16 + mc * 4 + pt) * 128 + ww * 16 + p] = o;
      }
    }
  }
}

extern "C" void kernel_launch(void* const* d_in, const int* in_sizes, int n_in,
                              void* d_out, int out_size, void* d_ws, size_t ws_size,
                              hipStream_t stream) {
  const float* x     = (const float*)d_in[0];
  const float* Wq    = (const float*)d_in[1];
  const float* Wk    = (const float*)d_in[2];
  const float* Wv    = (const float*)d_in[3];
  const float* gamma = (const float*)d_in[4];
  const float* W1    = (const float*)d_in[5];
  const float* b1    = (const float*)d_in[6];
  const float* W2    = (const float*)d_in[7];
  const float* b2    = (const float*)d_in[8];
  const float* ln1w  = (const float*)d_in[9];
  const float* ln1b  = (const float*)d_in[10];
  const float* ln2w  = (const float*)d_in[11];
  const float* ln2b  = (const float*)d_in[12];
  float* out = (float*)d_out;

  char* wsb = (char*)d_ws;
  unsigned short* XAfrag = (unsigned short*)wsb;                 // 67108864 B, frag order
  unsigned short* Vw     = (unsigned short*)(wsb + 67108864);    // 67108864 B
  unsigned short* Xfrag  = (unsigned short*)(wsb + 134217728);   // 67108864 B, frag order
  unsigned short* Qw     = (unsigned short*)(wsb + 201326592);   // 8388608 B
  unsigned short* Kw     = (unsigned short*)(wsb + 209715200);   // 8388608 B
  unsigned short* Wqkv   = (unsigned short*)(wsb + 218103808);   // 163840 B
  unsigned short* W1s    = (unsigned short*)(wsb + 218267648);   // 524288 B
  unsigned short* W2s    = (unsigned short*)(wsb + 218791936);   // 524288 B -> end ~209 MB

  prep_weights<<<1024, 256, 0, stream>>>(Wq, Wk, Wv, W1, W2, Wqkv, W1s, W2s);
  xprep_kernel<<<16384, 256, 0, stream>>>(x, Xfrag);
  qkvproj_kernel<<<2048, 256, 0, stream>>>(Xfrag, Wqkv, Qw, Kw, Vw);
  attn_fused_kernel<<<512, 1024, 0, stream>>>(Qw, Kw, Vw, Xfrag, gamma, XAfrag);
  ffn_mfma_kernel<<<2048, 256, 0, stream>>>(XAfrag, W1s, W2s, b1, b2, ln1w, ln1b, ln2w, ln2b, out);
}

// Round 4
// 672.255 us; speedup vs baseline: 1.5063x; 1.5063x over previous
//
#include <hip/hip_runtime.h>
#include <hip/hip_bf16.h>

#define C_DIM 256
#define HW_DIM 16384
#define F_DIM 1024

typedef __hip_bfloat16 bf16;
typedef short short8 __attribute__((ext_vector_type(8)));
typedef float f32x4 __attribute__((ext_vector_type(4)));

__device__ __forceinline__ float bf2f(unsigned short u) {
  unsigned int x = ((unsigned int)u) << 16;
  return __uint_as_float(x);
}
__device__ __forceinline__ unsigned short f2bfbits(float v) {
  bf16 h = __float2bfloat16(v);
  return *(unsigned short*)&h;
}

// Fragment layout used for X and XA (per window):
//   FR(win, mt, ks, l, j) at ((((win*16)+mt)*8+ks)*64+l)*8+j
//   = X[c = ks*32 + (l>>4)*8 + j][token n = mt*16 + (l&15)]
// This is exactly the MFMA B-fragment order: a wave's 64 lanes reading
// (mt, ks) get their short8 as one contiguous 1 KiB block.

// ---------------- kernel 0: weight prep ----------------
__global__ __launch_bounds__(256) void prep_weights(
    const float* __restrict__ Wq, const float* __restrict__ Wk,
    const float* __restrict__ Wv, const float* __restrict__ W1,
    const float* __restrict__ W2, unsigned short* __restrict__ Wqkv,
    unsigned short* __restrict__ W1s, unsigned short* __restrict__ W2s) {
  int i = blockIdx.x * 256 + threadIdx.x;
  if (i < 320 * 256) {
    int r = i >> 8, c = i & 255;
    float v;
    if (r < 32)      v = Wq[r * 256 + c];
    else if (r < 64) v = Wk[(r - 32) * 256 + c];
    else             v = Wv[(r - 64) * 256 + c];
    Wqkv[i] = f2bfbits(v);
  }
  if (i < 32768) {
    int ft = i >> 9, ks = (i >> 6) & 7, l = i & 63;
    int f = ft * 16 + (l & 15), kb = ks * 32 + (l >> 4) * 8;
    #pragma unroll
    for (int j = 0; j < 8; ++j)
      W1s[i * 8 + j] = f2bfbits(W1[f * 256 + kb + j]);
  }
  if (i < 32768) {
    int ct = i >> 11, gks = (i >> 6) & 31, l = i & 63;
    int c = ct * 16 + (l & 15), fb = gks * 32 + (l >> 4) * 8;
    #pragma unroll
    for (int j = 0; j < 8; ++j)
      W2s[i * 8 + j] = f2bfbits(W2[c * 1024 + fb + j]);
  }
}

// ---------------- kernel 0b: x -> Xfrag (fragment-order bf16 transpose) ----------------
__global__ __launch_bounds__(256) void xprep_kernel(
    const float* __restrict__ x, unsigned short* __restrict__ Xfrag) {
  const int gtid = blockIdx.x * 256 + threadIdx.x;   // [0, 4194304)
  const int win = gtid >> 13;
  const int rem = gtid & 8191;
  const int mt = rem >> 9, ks = (rem >> 6) & 7, l = rem & 63;
  const int t = l & 15, q = l >> 4;
  const int b = win >> 6, wh = (win >> 3) & 7, ww = win & 7;
  const int h = wh * 16 + mt, w = ww * 16 + t;
  const int c0 = ks * 32 + q * 8;
  const float* xp = x + ((size_t)(b * 256 + c0) * 128 + h) * 128 + w;
  short8 v;
  #pragma unroll
  for (int j = 0; j < 8; ++j)
    v[j] = (short)f2bfbits(xp[(size_t)j * 16384]);
  *(short8*)(Xfrag + (size_t)gtid * 8) = v;
}

// ---------------- kernel 1: QKV projection (LDS-free, barrier-free) ----------------
__global__ __launch_bounds__(256) void qkvproj_kernel(
    const unsigned short* __restrict__ Xfrag, const unsigned short* __restrict__ Wqkv,
    unsigned short* __restrict__ Qw, unsigned short* __restrict__ Kw,
    unsigned short* __restrict__ Vw) {
  const int bid = blockIdx.x;
  const int win = bid >> 2, mc = bid & 3;
  const int m0 = mc * 64;
  const int tid = threadIdx.x;
  const int wv = tid >> 6, l = tid & 63;
  const int t = l & 15, q = l >> 4;
  const unsigned short* Xb = Xfrag + (size_t)win * 65536;

  for (int mt = 0; mt < 4; ++mt) {
    short8 Bf[8];
    #pragma unroll
    for (int ks = 0; ks < 8; ++ks)
      Bf[ks] = *(const short8*)(Xb + (((size_t)(mc * 4 + mt) * 8 + ks) * 64 + l) * 8);
    #pragma unroll
    for (int rti = 0; rti < 5; ++rti) {
      const int rt = wv * 5 + rti;
      const int r0 = rt * 16;
      f32x4 acc = (f32x4){0.f, 0.f, 0.f, 0.f};
      #pragma unroll
      for (int ks = 0; ks < 8; ++ks) {
        short8 av = *(const short8*)(Wqkv + (size_t)(r0 + t) * 256 + ks * 32 + q * 8);
        acc = __builtin_amdgcn_mfma_f32_16x16x32_bf16(av, Bf[ks], acc, 0, 0, 0);
      }
      const int n = m0 + mt * 16 + t;   // token
      if (rt < 4) {
        ushort4 u;
        u.x = f2bfbits(acc[0]); u.y = f2bfbits(acc[1]);
        u.z = f2bfbits(acc[2]); u.w = f2bfbits(acc[3]);
        unsigned short* dst = (rt < 2) ? Qw : Kw;
        int o0 = (rt & 1) * 16 + q * 4;
        *(ushort4*)(dst + ((size_t)win * 256 + n) * 32 + o0) = u;
      } else {
        #pragma unroll
        for (int r = 0; r < 4; ++r) {
          int c = r0 - 64 + q * 4 + r;
          Vw[((size_t)win * 256 + c) * 256 + n] = f2bfbits(acc[r]);
        }
      }
    }
  }
}

// ---------------- kernel 2: fused window attention ----------------
__global__ __launch_bounds__(1024) void attn_fused_kernel(
    const unsigned short* __restrict__ Qw, const unsigned short* __restrict__ Kw,
    const unsigned short* __restrict__ Vw, const unsigned short* __restrict__ Xfrag,
    const float* __restrict__ gamma, unsigned short* __restrict__ XAfrag) {
  __shared__ __align__(16) short Ps[256][72];  // 36864 B
  __shared__ float Lpart[4][4][64];
  __shared__ float Ls[256];

  const int win = blockIdx.x;
  const int tid = threadIdx.x;
  const int wid = tid >> 6, l = tid & 63;
  const int t = l & 15, q = l >> 4;
  const int wr = wid >> 2, wc = wid & 3;

  f32x4 Oacc[4][4];   // [k: c-tile][i: n-tile]
  #pragma unroll
  for (int k = 0; k < 4; ++k)
    #pragma unroll
    for (int i = 0; i < 4; ++i)
      Oacc[k][i] = (f32x4){0.f, 0.f, 0.f, 0.f};
  float lsum[16];
  #pragma unroll
  for (int e = 0; e < 16; ++e) lsum[e] = 0.f;

  const unsigned short* Qb = Qw + (size_t)win * 256 * 32;
  const unsigned short* Kb = Kw + (size_t)win * 256 * 32;
  const unsigned short* Vb = Vw + (size_t)win * 65536;

  short8 aq[4];
  #pragma unroll
  for (int i = 0; i < 4; ++i)
    aq[i] = *(const short8*)(Qb + (size_t)((wr * 4 + i) * 16 + t) * 32 + q * 8);

  for (int mcc = 0; mcc < 4; ++mcc) {
    // ---- S chunk ----
    {
      const int m0s = (mcc * 4 + wc) * 16;
      short8 bk = *(const short8*)(Kb + (size_t)(m0s + t) * 32 + q * 8);
      f32x4 sv[4];
      #pragma unroll
      for (int i = 0; i < 4; ++i)
        sv[i] = __builtin_amdgcn_mfma_f32_16x16x32_bf16(aq[i], bk, (f32x4){0.f,0.f,0.f,0.f}, 0, 0, 0);
      #pragma unroll
      for (int i = 0; i < 4; ++i) {
        #pragma unroll
        for (int r = 0; r < 4; ++r) {
          float e = __expf(sv[i][r]);
          lsum[i * 4 + r] += e;
          Ps[(wr * 4 + i) * 16 + q * 4 + r][wc * 16 + t] = (short)f2bfbits(e);
        }
      }
    }
    __syncthreads();
    // ---- PV chunk (swapped) ----
    #pragma unroll
    for (int ks2 = 0; ks2 < 2; ++ks2) {
      short8 ap[4], bv[4];
      #pragma unroll
      for (int i = 0; i < 4; ++i)
        ap[i] = *(const short8*)&Ps[(wr * 4 + i) * 16 + t][ks2 * 32 + q * 8];
      #pragma unroll
      for (int k = 0; k < 4; ++k)
        bv[k] = *(const short8*)(Vb + (size_t)((wc * 4 + k) * 16 + t) * 256 + mcc * 64 + ks2 * 32 + q * 8);
      #pragma unroll
      for (int k = 0; k < 4; ++k)
        #pragma unroll
        for (int i = 0; i < 4; ++i)
          Oacc[k][i] = __builtin_amdgcn_mfma_f32_16x16x32_bf16(bv[k], ap[i], Oacc[k][i], 0, 0, 0);
    }
    __syncthreads();
  }

  // ---- row sums ----
  #pragma unroll
  for (int mask = 1; mask < 16; mask <<= 1)
    #pragma unroll
    for (int e = 0; e < 16; ++e)
      lsum[e] += __shfl_xor(lsum[e], mask);
  if (t == 0) {
    #pragma unroll
    for (int i = 0; i < 4; ++i)
      *(float4*)&Lpart[wr][wc][i * 16 + q * 4] =
          make_float4(lsum[i * 4 + 0], lsum[i * 4 + 1], lsum[i * 4 + 2], lsum[i * 4 + 3]);
  }
  __syncthreads();
  if (tid < 256) {
    int wrr = tid >> 6, nl = tid & 63;
    float s = Lpart[wrr][0][nl] + Lpart[wrr][1][nl] + Lpart[wrr][2][nl] + Lpart[wrr][3][nl];
    Ls[tid] = gamma[0] / s;
  }
  __syncthreads();

  // ---- epilogue: frag-order residual + frag-order store ----
  const unsigned short* Xres = Xfrag + (size_t)win * 65536;
  unsigned short* XAb = XAfrag + (size_t)win * 65536;
  #pragma unroll
  for (int i = 0; i < 4; ++i) {
    const int n = (wr * 4 + i) * 16 + t;
    const float ls = Ls[n];
    #pragma unroll
    for (int k = 0; k < 4; ++k) {
      const size_t off = (((size_t)(wr * 4 + i) * 8 + wc * 2 + (k >> 1)) * 64 +
                          ((k & 1) * 2 + (q >> 1)) * 16 + t) * 8 + (q & 1) * 4;
      ushort4 xa4 = *(const ushort4*)(Xres + off);
      const unsigned short* xp = (const unsigned short*)&xa4;
      ushort4 u;
      unsigned short* up = (unsigned short*)&u;
      #pragma unroll
      for (int r = 0; r < 4; ++r)
        up[r] = f2bfbits(ls * Oacc[k][i][r] + bf2f(xp[r]));
      *(ushort4*)(XAb + off) = u;
    }
  }
}

// ---------------- kernel 3: fused MFMA FFN + both LayerNorms ----------------
// block = (win, mc): 64 pixels. X tile staged ONCE into LDS in fragment order
// (linear 32 KB copy: coalesced global, conflict-free LDS). B-frags are
// contiguous conflict-free ds_read_b128. LDS 52224 B -> 3 blocks/CU.
__global__ __launch_bounds__(256, 3) void ffn_mfma_kernel(
    const unsigned short* __restrict__ XAfrag,
    const unsigned short* __restrict__ W1s, const unsigned short* __restrict__ W2s,
    const float* __restrict__ b1, const float* __restrict__ b2,
    const float* __restrict__ ln1w, const float* __restrict__ ln1b,
    const float* __restrict__ ln2w, const float* __restrict__ ln2b,
    float* __restrict__ out) {
  __shared__ __align__(16) short Xf[4][8][64][8];  // 32768 B, frag order [pt][ks][l][j]
  __shared__ __align__(16) short Ht[64][136];      // 17408 B
  __shared__ float red[2][4][64];                  // 2048 B

  const int bid = blockIdx.x;
  const int win = bid >> 2, mc = bid & 3;
  const int b = win >> 6, wh = (win >> 3) & 7, ww = win & 7;
  const int tid = threadIdx.x;
  const int wv = tid >> 6, l = tid & 63;
  const int p = l & 15, q = l >> 4;
  // block's contiguous 32 KB fragment chunk: mt = mc*4 .. mc*4+3
  const unsigned short* XAb = XAfrag + (size_t)win * 65536 + (size_t)mc * 16384;

  // stage: linear copy, 8 x short8 per thread
  {
    const short8* src = (const short8*)XAb;
    short8* dst = (short8*)&Xf[0][0][0][0];
    #pragma unroll
    for (int rep = 0; rep < 8; ++rep)
      dst[rep * 256 + tid] = src[rep * 256 + tid];
  }
  __syncthreads();

  f32x4 Yacc[4][4];
  #pragma unroll
  for (int i = 0; i < 4; ++i)
    #pragma unroll
    for (int pt = 0; pt < 4; ++pt)
      Yacc[i][pt] = (f32x4){0.f, 0.f, 0.f, 0.f};

  const short8* W1s8 = (const short8*)W1s;
  const short8* W2s8 = (const short8*)W2s;

  for (int fc = 0; fc < 8; ++fc) {
    f32x4 Hacc[2][4];
    #pragma unroll
    for (int i = 0; i < 2; ++i)
      #pragma unroll
      for (int pt = 0; pt < 4; ++pt)
        Hacc[i][pt] = (f32x4){0.f, 0.f, 0.f, 0.f};
    const int f0 = (fc * 8 + wv * 2) * 8;
    #pragma unroll
    for (int ks = 0; ks < 8; ++ks) {
      short8 a0 = W1s8[(f0 + ks) * 64 + l];
      short8 a1 = W1s8[(f0 + 8 + ks) * 64 + l];
      #pragma unroll
      for (int pt = 0; pt < 4; ++pt) {
        short8 bf = *(const short8*)&Xf[pt][ks][l][0];
        Hacc[0][pt] = __builtin_amdgcn_mfma_f32_16x16x32_bf16(a0, bf, Hacc[0][pt], 0, 0, 0);
        Hacc[1][pt] = __builtin_amdgcn_mfma_f32_16x16x32_bf16(a1, bf, Hacc[1][pt], 0, 0, 0);
      }
    }
    __syncthreads();   // all waves finished reading Ht (previous fc's Y-GEMM)
    // bias + GELU -> Ht
    #pragma unroll
    for (int i = 0; i < 2; ++i) {
      float4 bv1 = *(const float4*)(b1 + fc * 128 + wv * 32 + i * 16 + q * 4);
      #pragma unroll
      for (int pt = 0; pt < 4; ++pt) {
        ushort4 hbv;
        unsigned short* hp = (unsigned short*)&hbv;
        #pragma unroll
        for (int r = 0; r < 4; ++r) {
          float v = Hacc[i][pt][r] + ((const float*)&bv1)[r];
          float u = 0.7978845608f * fmaf(0.044715f * v, v * v, v);
          float e = __expf(2.f * u);
          float g = v - v / (e + 1.f);
          hp[r] = f2bfbits(g);
        }
        *(ushort4*)&Ht[pt * 16 + p][wv * 32 + i * 16 + q * 4] = hbv;
      }
    }
    __syncthreads();   // Ht ready
    #pragma unroll
    for (int fs = 0; fs < 4; ++fs) {
      short8 av[4];
      #pragma unroll
      for (int i = 0; i < 4; ++i)
        av[i] = W2s8[((wv * 4 + i) * 32 + fc * 4 + fs) * 64 + l];
      #pragma unroll
      for (int pt = 0; pt < 4; ++pt) {
        short8 bf = *(const short8*)&Ht[pt * 16 + p][fs * 32 + q * 8];
        #pragma unroll
        for (int i = 0; i < 4; ++i)
          Yacc[i][pt] = __builtin_amdgcn_mfma_f32_16x16x32_bf16(av[i], bf, Yacc[i][pt], 0, 0, 0);
      }
    }
  }

  // bias b2
  #pragma unroll
  for (int i = 0; i < 4; ++i) {
    float4 bb = *(const float4*)(b2 + wv * 64 + i * 16 + q * 4);
    #pragma unroll
    for (int pt = 0; pt < 4; ++pt)
      #pragma unroll
      for (int r = 0; r < 4; ++r)
        Yacc[i][pt][r] += ((const float*)&bb)[r];
  }

  // LN1 stats
  #pragma unroll
  for (int pt = 0; pt < 4; ++pt) {
    float ss = 0.f, sq = 0.f;
    #pragma unroll
    for (int i = 0; i < 4; ++i)
      #pragma unroll
      for (int r = 0; r < 4; ++r) { float v = Yacc[i][pt][r]; ss += v; sq += v * v; }
    ss += __shfl_xor(ss, 16); sq += __shfl_xor(sq, 16);
    ss += __shfl_xor(ss, 32); sq += __shfl_xor(sq, 32);
    if (l < 16) { red[0][wv][pt * 16 + l] = ss; red[1][wv][pt * 16 + l] = sq; }
  }
  __syncthreads();
  if (tid < 64) {
    float S  = red[0][0][tid] + red[0][1][tid] + red[0][2][tid] + red[0][3][tid];
    float Q2 = red[1][0][tid] + red[1][1][tid] + red[1][2][tid] + red[1][3][tid];
    float m = S * 0.00390625f;
    float va = Q2 * 0.00390625f - m * m;
    red[0][0][tid] = m; red[1][0][tid] = rsqrtf(va + 1e-5f);
  }
  __syncthreads();
  // x2 = xa + LN1(y); xa re-read from Xf (LDS, frag-order)
  #pragma unroll
  for (int i = 0; i < 4; ++i) {
    float4 w1v = *(const float4*)(ln1w + wv * 64 + i * 16 + q * 4);
    float4 b1v = *(const float4*)(ln1b + wv * 64 + i * 16 + q * 4);
    const int ksx = wv * 2 + (i >> 1);
    const int lq = (i & 1) * 2 + (q >> 1);
    #pragma unroll
    for (int pt = 0; pt < 4; ++pt) {
      int px = pt * 16 + p;
      float mu = red[0][0][px], rs = red[1][0][px];
      ushort4 xa4 = *(const ushort4*)&Xf[pt][ksx][lq * 16 + p][(q & 1) * 4];
      const unsigned short* xp = (const unsigned short*)&xa4;
      #pragma unroll
      for (int r = 0; r < 4; ++r)
        Yacc[i][pt][r] = bf2f(xp[r]) + (Yacc[i][pt][r] - mu) * rs * ((const float*)&w1v)[r] + ((const float*)&b1v)[r];
    }
  }
  __syncthreads();   // protect red[*][0][*] before stats-2 overwrites
  // LN2 stats
  #pragma unroll
  for (int pt = 0; pt < 4; ++pt) {
    float ss = 0.f, sq = 0.f;
    #pragma unroll
    for (int i = 0; i < 4; ++i)
      #pragma unroll
      for (int r = 0; r < 4; ++r) { float v = Yacc[i][pt][r]; ss += v; sq += v * v; }
    ss += __shfl_xor(ss, 16); sq += __shfl_xor(sq, 16);
    ss += __shfl_xor(ss, 32); sq += __shfl_xor(sq, 32);
    if (l < 16) { red[0][wv][pt * 16 + l] = ss; red[1][wv][pt * 16 + l] = sq; }
  }
  __syncthreads();
  if (tid < 64) {
    float S  = red[0][0][tid] + red[0][1][tid] + red[0][2][tid] + red[0][3][tid];
    float Q2 = red[1][0][tid] + red[1][1][tid] + red[1][2][tid] + red[1][3][tid];
    float m = S * 0.00390625f;
    float va = Q2 * 0.00390625f - m * m;
    red[0][0][tid] = m; red[1][0][tid] = rsqrtf(va + 1e-5f);
  }
  __syncthreads();
  // out = x2 + LN2(x2), NCHW
  #pragma unroll
  for (int i = 0; i < 4; ++i) {
    float4 w2v = *(const float4*)(ln2w + wv * 64 + i * 16 + q * 4);
    float4 b2v = *(const float4*)(ln2b + wv * 64 + i * 16 + q * 4);
    #pragma unroll
    for (int pt = 0; pt < 4; ++pt) {
      int px = pt * 16 + p;
      float mu = red[0][0][px], rs = red[1][0][px];
      #pragma unroll
      for (int r = 0; r < 4; ++r) {
        int c = wv * 64 + i * 16 + q * 4 + r;
        float x2 = Yacc[i][pt][r];
        float o = x2 + (x2 - mu) * rs * ((const float*)&w2v)[r] + ((const float*)&b2v)[r];
        out[(((size_t)(b * 256 + c) * 128) + wh * 16 + mc * 4 + pt) * 128 + ww * 16 + p] = o;
      }
    }
  }
}

extern "C" void kernel_launch(void* const* d_in, const int* in_sizes, int n_in,
                              void* d_out, int out_size, void* d_ws, size_t ws_size,
                              hipStream_t stream) {
  const float* x     = (const float*)d_in[0];
  const float* Wq    = (const float*)d_in[1];
  const float* Wk    = (const float*)d_in[2];
  const float* Wv    = (const float*)d_in[3];
  const float* gamma = (const float*)d_in[4];
  const float* W1    = (const float*)d_in[5];
  const float* b1    = (const float*)d_in[6];
  const float* W2    = (const float*)d_in[7];
  const float* b2    = (const float*)d_in[8];
  const float* ln1w  = (const float*)d_in[9];
  const float* ln1b  = (const float*)d_in[10];
  const float* ln2w  = (const float*)d_in[11];
  const float* ln2b  = (const float*)d_in[12];
  float* out = (float*)d_out;

  char* wsb = (char*)d_ws;
  unsigned short* XAfrag = (unsigned short*)wsb;                 // 67108864 B, frag order
  unsigned short* Vw     = (unsigned short*)(wsb + 67108864);    // 67108864 B
  unsigned short* Xfrag  = (unsigned short*)(wsb + 134217728);   // 67108864 B, frag order
  unsigned short* Qw     = (unsigned short*)(wsb + 201326592);   // 8388608 B
  unsigned short* Kw     = (unsigned short*)(wsb + 209715200);   // 8388608 B
  unsigned short* Wqkv   = (unsigned short*)(wsb + 218103808);   // 163840 B
  unsigned short* W1s    = (unsigned short*)(wsb + 218267648);   // 524288 B
  unsigned short* W2s    = (unsigned short*)(wsb + 218791936);   // 524288 B -> end ~209 MB

  prep_weights<<<1024, 256, 0, stream>>>(Wq, Wk, Wv, W1, W2, Wqkv, W1s, W2s);
  xprep_kernel<<<16384, 256, 0, stream>>>(x, Xfrag);
  qkvproj_kernel<<<2048, 256, 0, stream>>>(Xfrag, Wqkv, Qw, Kw, Vw);
  attn_fused_kernel<<<512, 1024, 0, stream>>>(Qw, Kw, Vw, Xfrag, gamma, XAfrag);
  ffn_mfma_kernel<<<2048, 256, 0, stream>>>(XAfrag, W1s, W2s, b1, b2, ln1w, ln1b, ln2w, ln2b, out);
}

// Round 5
// 671.465 us; speedup vs baseline: 1.5081x; 1.0012x over previous
//
#include <hip/hip_runtime.h>
#include <hip/hip_bf16.h>

#define C_DIM 256
#define HW_DIM 16384
#define F_DIM 1024

typedef __hip_bfloat16 bf16;
typedef short short8 __attribute__((ext_vector_type(8)));
typedef float f32x4 __attribute__((ext_vector_type(4)));

__device__ __forceinline__ float bf2f(unsigned short u) {
  unsigned int x = ((unsigned int)u) << 16;
  return __uint_as_float(x);
}
__device__ __forceinline__ unsigned short f2bfbits(float v) {
  bf16 h = __float2bfloat16(v);
  return *(unsigned short*)&h;
}

// Fragment layout used for X and XA (per window):
//   FR(win, mt, ks, l, j) at ((((win*16)+mt)*8+ks)*64+l)*8+j
//   = X[c = ks*32 + (l>>4)*8 + j][token n = mt*16 + (l&15)]

// ---------------- kernel 0: weight prep ----------------
__global__ __launch_bounds__(256) void prep_weights(
    const float* __restrict__ Wq, const float* __restrict__ Wk,
    const float* __restrict__ Wv, const float* __restrict__ W1,
    const float* __restrict__ W2, unsigned short* __restrict__ Wqkv,
    unsigned short* __restrict__ W1s, unsigned short* __restrict__ W2s) {
  int i = blockIdx.x * 256 + threadIdx.x;
  if (i < 320 * 256) {
    int r = i >> 8, c = i & 255;
    float v;
    if (r < 32)      v = Wq[r * 256 + c];
    else if (r < 64) v = Wk[(r - 32) * 256 + c];
    else             v = Wv[(r - 64) * 256 + c];
    Wqkv[i] = f2bfbits(v);
  }
  if (i < 32768) {
    int ft = i >> 9, ks = (i >> 6) & 7, l = i & 63;
    int f = ft * 16 + (l & 15), kb = ks * 32 + (l >> 4) * 8;
    #pragma unroll
    for (int j = 0; j < 8; ++j)
      W1s[i * 8 + j] = f2bfbits(W1[f * 256 + kb + j]);
  }
  if (i < 32768) {
    int ct = i >> 11, gks = (i >> 6) & 31, l = i & 63;
    int c = ct * 16 + (l & 15), fb = gks * 32 + (l >> 4) * 8;
    #pragma unroll
    for (int j = 0; j < 8; ++j)
      W2s[i * 8 + j] = f2bfbits(W2[c * 1024 + fb + j]);
  }
}

// ---------------- kernel 0b: x -> Xfrag (fragment-order bf16 transpose) ----------------
__global__ __launch_bounds__(256) void xprep_kernel(
    const float* __restrict__ x, unsigned short* __restrict__ Xfrag) {
  const int gtid = blockIdx.x * 256 + threadIdx.x;   // [0, 4194304)
  const int win = gtid >> 13;
  const int rem = gtid & 8191;
  const int mt = rem >> 9, ks = (rem >> 6) & 7, l = rem & 63;
  const int t = l & 15, q = l >> 4;
  const int b = win >> 6, wh = (win >> 3) & 7, ww = win & 7;
  const int h = wh * 16 + mt, w = ww * 16 + t;
  const int c0 = ks * 32 + q * 8;
  const float* xp = x + ((size_t)(b * 256 + c0) * 128 + h) * 128 + w;
  short8 v;
  #pragma unroll
  for (int j = 0; j < 8; ++j)
    v[j] = (short)f2bfbits(xp[(size_t)j * 16384]);
  *(short8*)(Xfrag + (size_t)gtid * 8) = v;
}

// ---------------- kernel 1: QKV projection (LDS-free, barrier-free) ----------------
__global__ __launch_bounds__(256) void qkvproj_kernel(
    const unsigned short* __restrict__ Xfrag, const unsigned short* __restrict__ Wqkv,
    unsigned short* __restrict__ Qw, unsigned short* __restrict__ Kw,
    unsigned short* __restrict__ Vw) {
  const int bid = blockIdx.x;
  const int win = bid >> 2, mc = bid & 3;
  const int m0 = mc * 64;
  const int tid = threadIdx.x;
  const int wv = tid >> 6, l = tid & 63;
  const int t = l & 15, q = l >> 4;
  const unsigned short* Xb = Xfrag + (size_t)win * 65536;

  for (int mt = 0; mt < 4; ++mt) {
    short8 Bf[8];
    #pragma unroll
    for (int ks = 0; ks < 8; ++ks)
      Bf[ks] = *(const short8*)(Xb + (((size_t)(mc * 4 + mt) * 8 + ks) * 64 + l) * 8);
    #pragma unroll
    for (int rti = 0; rti < 5; ++rti) {
      const int rt = wv * 5 + rti;
      const int r0 = rt * 16;
      f32x4 acc = (f32x4){0.f, 0.f, 0.f, 0.f};
      #pragma unroll
      for (int ks = 0; ks < 8; ++ks) {
        short8 av = *(const short8*)(Wqkv + (size_t)(r0 + t) * 256 + ks * 32 + q * 8);
        acc = __builtin_amdgcn_mfma_f32_16x16x32_bf16(av, Bf[ks], acc, 0, 0, 0);
      }
      const int n = m0 + mt * 16 + t;   // token
      if (rt < 4) {
        ushort4 u;
        u.x = f2bfbits(acc[0]); u.y = f2bfbits(acc[1]);
        u.z = f2bfbits(acc[2]); u.w = f2bfbits(acc[3]);
        unsigned short* dst = (rt < 2) ? Qw : Kw;
        int o0 = (rt & 1) * 16 + q * 4;
        *(ushort4*)(dst + ((size_t)win * 256 + n) * 32 + o0) = u;
      } else {
        #pragma unroll
        for (int r = 0; r < 4; ++r) {
          int c = r0 - 64 + q * 4 + r;
          Vw[((size_t)win * 256 + c) * 256 + n] = f2bfbits(acc[r]);
        }
      }
    }
  }
}

// ---------------- kernel 2: fused window attention (4-wave blocks) ----------------
// block = (win, wr): 64 tokens, 4 waves (wave id = wc). Double-buffered Ps ->
// ONE barrier per mcc. XCD swizzle keeps a window's 4 blocks on one XCD so the
// 128 KB V tile is L2-resident across its 4 re-reads.
__global__ __launch_bounds__(256, 4) void attn_fused_kernel(
    const unsigned short* __restrict__ Qw, const unsigned short* __restrict__ Kw,
    const unsigned short* __restrict__ Vw, const unsigned short* __restrict__ Xfrag,
    const float* __restrict__ gamma, unsigned short* __restrict__ XAfrag) {
  __shared__ __align__(16) short Ps[2][64][72];   // 18432 B
  __shared__ float Lpart[4][64];
  __shared__ float Ls[64];

  // bijective XCD swizzle (2048 % 8 == 0): window w's 4 blocks share an XCD
  const int bid = blockIdx.x;
  const int wgb = (bid & 7) * 256 + (bid >> 3);
  const int win = wgb >> 2, wr = wgb & 3;

  const int tid = threadIdx.x;
  const int wc = tid >> 6, l = tid & 63;
  const int t = l & 15, q = l >> 4;

  f32x4 Oacc[4][4];   // [k: c-tile][i: n-tile]
  #pragma unroll
  for (int k = 0; k < 4; ++k)
    #pragma unroll
    for (int i = 0; i < 4; ++i)
      Oacc[k][i] = (f32x4){0.f, 0.f, 0.f, 0.f};
  float lsum[16];
  #pragma unroll
  for (int e = 0; e < 16; ++e) lsum[e] = 0.f;

  const unsigned short* Qb = Qw + (size_t)win * 256 * 32;
  const unsigned short* Kb = Kw + (size_t)win * 256 * 32;
  const unsigned short* Vb = Vw + (size_t)win * 65536;

  short8 aq[4];
  #pragma unroll
  for (int i = 0; i < 4; ++i)
    aq[i] = *(const short8*)(Qb + (size_t)((wr * 4 + i) * 16 + t) * 32 + q * 8);

  for (int mcc = 0; mcc < 4; ++mcc) {
    const int buf = mcc & 1;
    // ---- S chunk: this wave: m-tile mcc*4+wc, n-tiles wr*4+0..3 ----
    {
      const int m0s = (mcc * 4 + wc) * 16;
      short8 bk = *(const short8*)(Kb + (size_t)(m0s + t) * 32 + q * 8);
      f32x4 sv[4];
      #pragma unroll
      for (int i = 0; i < 4; ++i)
        sv[i] = __builtin_amdgcn_mfma_f32_16x16x32_bf16(aq[i], bk, (f32x4){0.f,0.f,0.f,0.f}, 0, 0, 0);
      #pragma unroll
      for (int i = 0; i < 4; ++i) {
        #pragma unroll
        for (int r = 0; r < 4; ++r) {
          float e = __expf(sv[i][r]);
          lsum[i * 4 + r] += e;
          Ps[buf][i * 16 + q * 4 + r][wc * 16 + t] = (short)f2bfbits(e);
        }
      }
    }
    __syncthreads();   // Ps[buf] ready (and Ps[buf^1]'s PV from mcc-1 complete on all waves before next overwrite)
    // ---- PV chunk (swapped): O^T[c][n] += V[c, chunk] @ P^T[chunk, n] ----
    #pragma unroll
    for (int ks2 = 0; ks2 < 2; ++ks2) {
      short8 ap[4], bv[4];
      #pragma unroll
      for (int i = 0; i < 4; ++i)
        ap[i] = *(const short8*)&Ps[buf][i * 16 + t][ks2 * 32 + q * 8];
      #pragma unroll
      for (int k = 0; k < 4; ++k)
        bv[k] = *(const short8*)(Vb + (size_t)((wc * 4 + k) * 16 + t) * 256 + mcc * 64 + ks2 * 32 + q * 8);
      #pragma unroll
      for (int k = 0; k < 4; ++k)
        #pragma unroll
        for (int i = 0; i < 4; ++i)
          Oacc[k][i] = __builtin_amdgcn_mfma_f32_16x16x32_bf16(bv[k], ap[i], Oacc[k][i], 0, 0, 0);
    }
    // no second barrier: next S writes the other Ps buffer
  }

  // ---- row sums: reduce over the 16 col-lanes, combine across the 4 waves ----
  #pragma unroll
  for (int mask = 1; mask < 16; mask <<= 1)
    #pragma unroll
    for (int e = 0; e < 16; ++e)
      lsum[e] += __shfl_xor(lsum[e], mask);
  __syncthreads();   // all PV reads of Ps done before Lpart reuse phase (and orders below)
  if (t == 0) {
    #pragma unroll
    for (int i = 0; i < 4; ++i)
      *(float4*)&Lpart[wc][i * 16 + q * 4] =
          make_float4(lsum[i * 4 + 0], lsum[i * 4 + 1], lsum[i * 4 + 2], lsum[i * 4 + 3]);
  }
  __syncthreads();
  if (tid < 64) {
    float s = Lpart[0][tid] + Lpart[1][tid] + Lpart[2][tid] + Lpart[3][tid];
    Ls[tid] = gamma[0] / s;
  }
  __syncthreads();

  // ---- epilogue: frag-order residual + frag-order store ----
  const unsigned short* Xres = Xfrag + (size_t)win * 65536;
  unsigned short* XAb = XAfrag + (size_t)win * 65536;
  #pragma unroll
  for (int i = 0; i < 4; ++i) {
    const float ls = Ls[i * 16 + t];
    #pragma unroll
    for (int k = 0; k < 4; ++k) {
      const size_t off = (((size_t)(wr * 4 + i) * 8 + wc * 2 + (k >> 1)) * 64 +
                          ((k & 1) * 2 + (q >> 1)) * 16 + t) * 8 + (q & 1) * 4;
      ushort4 xa4 = *(const ushort4*)(Xres + off);
      const unsigned short* xp = (const unsigned short*)&xa4;
      ushort4 u;
      unsigned short* up = (unsigned short*)&u;
      #pragma unroll
      for (int r = 0; r < 4; ++r)
        up[r] = f2bfbits(ls * Oacc[k][i][r] + bf2f(xp[r]));
      *(ushort4*)(XAb + off) = u;
    }
  }
}

// ---------------- kernel 3: fused MFMA FFN + both LayerNorms ----------------
__global__ __launch_bounds__(256, 3) void ffn_mfma_kernel(
    const unsigned short* __restrict__ XAfrag,
    const unsigned short* __restrict__ W1s, const unsigned short* __restrict__ W2s,
    const float* __restrict__ b1, const float* __restrict__ b2,
    const float* __restrict__ ln1w, const float* __restrict__ ln1b,
    const float* __restrict__ ln2w, const float* __restrict__ ln2b,
    float* __restrict__ out) {
  __shared__ __align__(16) short Xf[4][8][64][8];  // 32768 B, frag order [pt][ks][l][j]
  __shared__ __align__(16) short Ht[64][136];      // 17408 B
  __shared__ float red[2][4][64];                  // 2048 B

  const int bid = blockIdx.x;
  const int win = bid >> 2, mc = bid & 3;
  const int b = win >> 6, wh = (win >> 3) & 7, ww = win & 7;
  const int tid = threadIdx.x;
  const int wv = tid >> 6, l = tid & 63;
  const int p = l & 15, q = l >> 4;
  const unsigned short* XAb = XAfrag + (size_t)win * 65536 + (size_t)mc * 16384;

  // stage: linear copy, 8 x short8 per thread
  {
    const short8* src = (const short8*)XAb;
    short8* dst = (short8*)&Xf[0][0][0][0];
    #pragma unroll
    for (int rep = 0; rep < 8; ++rep)
      dst[rep * 256 + tid] = src[rep * 256 + tid];
  }
  __syncthreads();

  f32x4 Yacc[4][4];
  #pragma unroll
  for (int i = 0; i < 4; ++i)
    #pragma unroll
    for (int pt = 0; pt < 4; ++pt)
      Yacc[i][pt] = (f32x4){0.f, 0.f, 0.f, 0.f};

  const short8* W1s8 = (const short8*)W1s;
  const short8* W2s8 = (const short8*)W2s;

  for (int fc = 0; fc < 8; ++fc) {
    f32x4 Hacc[2][4];
    #pragma unroll
    for (int i = 0; i < 2; ++i)
      #pragma unroll
      for (int pt = 0; pt < 4; ++pt)
        Hacc[i][pt] = (f32x4){0.f, 0.f, 0.f, 0.f};
    const int f0 = (fc * 8 + wv * 2) * 8;
    #pragma unroll
    for (int ks = 0; ks < 8; ++ks) {
      short8 a0 = W1s8[(f0 + ks) * 64 + l];
      short8 a1 = W1s8[(f0 + 8 + ks) * 64 + l];
      #pragma unroll
      for (int pt = 0; pt < 4; ++pt) {
        short8 bf = *(const short8*)&Xf[pt][ks][l][0];
        Hacc[0][pt] = __builtin_amdgcn_mfma_f32_16x16x32_bf16(a0, bf, Hacc[0][pt], 0, 0, 0);
        Hacc[1][pt] = __builtin_amdgcn_mfma_f32_16x16x32_bf16(a1, bf, Hacc[1][pt], 0, 0, 0);
      }
    }
    __syncthreads();   // all waves finished reading Ht (previous fc's Y-GEMM)
    // bias + GELU -> Ht
    #pragma unroll
    for (int i = 0; i < 2; ++i) {
      float4 bv1 = *(const float4*)(b1 + fc * 128 + wv * 32 + i * 16 + q * 4);
      #pragma unroll
      for (int pt = 0; pt < 4; ++pt) {
        ushort4 hbv;
        unsigned short* hp = (unsigned short*)&hbv;
        #pragma unroll
        for (int r = 0; r < 4; ++r) {
          float v = Hacc[i][pt][r] + ((const float*)&bv1)[r];
          float u = 0.7978845608f * fmaf(0.044715f * v, v * v, v);
          float e = __expf(2.f * u);
          float g = v - v / (e + 1.f);
          hp[r] = f2bfbits(g);
        }
        *(ushort4*)&Ht[pt * 16 + p][wv * 32 + i * 16 + q * 4] = hbv;
      }
    }
    __syncthreads();   // Ht ready
    #pragma unroll
    for (int fs = 0; fs < 4; ++fs) {
      short8 av[4];
      #pragma unroll
      for (int i = 0; i < 4; ++i)
        av[i] = W2s8[((wv * 4 + i) * 32 + fc * 4 + fs) * 64 + l];
      #pragma unroll
      for (int pt = 0; pt < 4; ++pt) {
        short8 bf = *(const short8*)&Ht[pt * 16 + p][fs * 32 + q * 8];
        #pragma unroll
        for (int i = 0; i < 4; ++i)
          Yacc[i][pt] = __builtin_amdgcn_mfma_f32_16x16x32_bf16(av[i], bf, Yacc[i][pt], 0, 0, 0);
      }
    }
  }

  // bias b2
  #pragma unroll
  for (int i = 0; i < 4; ++i) {
    float4 bb = *(const float4*)(b2 + wv * 64 + i * 16 + q * 4);
    #pragma unroll
    for (int pt = 0; pt < 4; ++pt)
      #pragma unroll
      for (int r = 0; r < 4; ++r)
        Yacc[i][pt][r] += ((const float*)&bb)[r];
  }

  // LN1 stats
  #pragma unroll
  for (int pt = 0; pt < 4; ++pt) {
    float ss = 0.f, sq = 0.f;
    #pragma unroll
    for (int i = 0; i < 4; ++i)
      #pragma unroll
      for (int r = 0; r < 4; ++r) { float v = Yacc[i][pt][r]; ss += v; sq += v * v; }
    ss += __shfl_xor(ss, 16); sq += __shfl_xor(sq, 16);
    ss += __shfl_xor(ss, 32); sq += __shfl_xor(sq, 32);
    if (l < 16) { red[0][wv][pt * 16 + l] = ss; red[1][wv][pt * 16 + l] = sq; }
  }
  __syncthreads();
  if (tid < 64) {
    float S  = red[0][0][tid] + red[0][1][tid] + red[0][2][tid] + red[0][3][tid];
    float Q2 = red[1][0][tid] + red[1][1][tid] + red[1][2][tid] + red[1][3][tid];
    float m = S * 0.00390625f;
    float va = Q2 * 0.00390625f - m * m;
    red[0][0][tid] = m; red[1][0][tid] = rsqrtf(va + 1e-5f);
  }
  __syncthreads();
  // x2 = xa + LN1(y); xa re-read from Xf (LDS, frag-order)
  #pragma unroll
  for (int i = 0; i < 4; ++i) {
    float4 w1v = *(const float4*)(ln1w + wv * 64 + i * 16 + q * 4);
    float4 b1v = *(const float4*)(ln1b + wv * 64 + i * 16 + q * 4);
    const int ksx = wv * 2 + (i >> 1);
    const int lq = (i & 1) * 2 + (q >> 1);
    #pragma unroll
    for (int pt = 0; pt < 4; ++pt) {
      int px = pt * 16 + p;
      float mu = red[0][0][px], rs = red[1][0][px];
      ushort4 xa4 = *(const ushort4*)&Xf[pt][ksx][lq * 16 + p][(q & 1) * 4];
      const unsigned short* xp = (const unsigned short*)&xa4;
      #pragma unroll
      for (int r = 0; r < 4; ++r)
        Yacc[i][pt][r] = bf2f(xp[r]) + (Yacc[i][pt][r] - mu) * rs * ((const float*)&w1v)[r] + ((const float*)&b1v)[r];
    }
  }
  __syncthreads();   // protect red[*][0][*] before stats-2 overwrites
  // LN2 stats
  #pragma unroll
  for (int pt = 0; pt < 4; ++pt) {
    float ss = 0.f, sq = 0.f;
    #pragma unroll
    for (int i = 0; i < 4; ++i)
      #pragma unroll
      for (int r = 0; r < 4; ++r) { float v = Yacc[i][pt][r]; ss += v; sq += v * v; }
    ss += __shfl_xor(ss, 16); sq += __shfl_xor(sq, 16);
    ss += __shfl_xor(ss, 32); sq += __shfl_xor(sq, 32);
    if (l < 16) { red[0][wv][pt * 16 + l] = ss; red[1][wv][pt * 16 + l] = sq; }
  }
  __syncthreads();
  if (tid < 64) {
    float S  = red[0][0][tid] + red[0][1][tid] + red[0][2][tid] + red[0][3][tid];
    float Q2 = red[1][0][tid] + red[1][1][tid] + red[1][2][tid] + red[1][3][tid];
    float m = S * 0.00390625f;
    float va = Q2 * 0.00390625f - m * m;
    red[0][0][tid] = m; red[1][0][tid] = rsqrtf(va + 1e-5f);
  }
  __syncthreads();
  // out = x2 + LN2(x2), NCHW
  #pragma unroll
  for (int i = 0; i < 4; ++i) {
    float4 w2v = *(const float4*)(ln2w + wv * 64 + i * 16 + q * 4);
    float4 b2v = *(const float4*)(ln2b + wv * 64 + i * 16 + q * 4);
    #pragma unroll
    for (int pt = 0; pt < 4; ++pt) {
      int px = pt * 16 + p;
      float mu = red[0][0][px], rs = red[1][0][px];
      #pragma unroll
      for (int r = 0; r < 4; ++r) {
        int c = wv * 64 + i * 16 + q * 4 + r;
        float x2 = Yacc[i][pt][r];
        float o = x2 + (x2 - mu) * rs * ((const float*)&w2v)[r] + ((const float*)&b2v)[r];
        out[(((size_t)(b * 256 + c) * 128) + wh * 16 + mc * 4 + pt) * 128 + ww * 16 + p] = o;
      }
    }
  }
}

extern "C" void kernel_launch(void* const* d_in, const int* in_sizes, int n_in,
                              void* d_out, int out_size, void* d_ws, size_t ws_size,
                              hipStream_t stream) {
  const float* x     = (const float*)d_in[0];
  const float* Wq    = (const float*)d_in[1];
  const float* Wk    = (const float*)d_in[2];
  const float* Wv    = (const float*)d_in[3];
  const float* gamma = (const float*)d_in[4];
  const float* W1    = (const float*)d_in[5];
  const float* b1    = (const float*)d_in[6];
  const float* W2    = (const float*)d_in[7];
  const float* b2    = (const float*)d_in[8];
  const float* ln1w  = (const float*)d_in[9];
  const float* ln1b  = (const float*)d_in[10];
  const float* ln2w  = (const float*)d_in[11];
  const float* ln2b  = (const float*)d_in[12];
  float* out = (float*)d_out;

  char* wsb = (char*)d_ws;
  unsigned short* XAfrag = (unsigned short*)wsb;                 // 67108864 B, frag order
  unsigned short* Vw     = (unsigned short*)(wsb + 67108864);    // 67108864 B
  unsigned short* Xfrag  = (unsigned short*)(wsb + 134217728);   // 67108864 B, frag order
  unsigned short* Qw     = (unsigned short*)(wsb + 201326592);   // 8388608 B
  unsigned short* Kw     = (unsigned short*)(wsb + 209715200);   // 8388608 B
  unsigned short* Wqkv   = (unsigned short*)(wsb + 218103808);   // 163840 B
  unsigned short* W1s    = (unsigned short*)(wsb + 218267648);   // 524288 B
  unsigned short* W2s    = (unsigned short*)(wsb + 218791936);   // 524288 B -> end ~209 MB

  prep_weights<<<1024, 256, 0, stream>>>(Wq, Wk, Wv, W1, W2, Wqkv, W1s, W2s);
  xprep_kernel<<<16384, 256, 0, stream>>>(x, Xfrag);
  qkvproj_kernel<<<2048, 256, 0, stream>>>(Xfrag, Wqkv, Qw, Kw, Vw);
  attn_fused_kernel<<<2048, 256, 0, stream>>>(Qw, Kw, Vw, Xfrag, gamma, XAfrag);
  ffn_mfma_kernel<<<2048, 256, 0, stream>>>(XAfrag, W1s, W2s, b1, b2, ln1w, ln1b, ln2w, ln2b, out);
}

// Round 7
// 580.875 us; speedup vs baseline: 1.7433x; 1.1560x over previous
//
#include <hip/hip_runtime.h>
#include <hip/hip_bf16.h>

#define C_DIM 256
#define HW_DIM 16384
#define F_DIM 1024

typedef __hip_bfloat16 bf16;
typedef short short8 __attribute__((ext_vector_type(8)));
typedef float f32x4 __attribute__((ext_vector_type(4)));

__device__ __forceinline__ float bf2f(unsigned short u) {
  unsigned int x = ((unsigned int)u) << 16;
  return __uint_as_float(x);
}
__device__ __forceinline__ unsigned short f2bfbits(float v) {
  bf16 h = __float2bfloat16(v);
  return *(unsigned short*)&h;
}

// Fragment layout used for X and XA (per window):
//   FR(win, mt, ks, l, j) at ((((win*16)+mt)*8+ks)*64+l)*8+j
//   = X[c = ks*32 + (l>>4)*8 + j][token n = mt*16 + (l&15)]

// ---------------- kernel 0: weight prep ----------------
__global__ __launch_bounds__(256) void prep_weights(
    const float* __restrict__ Wq, const float* __restrict__ Wk,
    const float* __restrict__ Wv, const float* __restrict__ W1,
    const float* __restrict__ W2, unsigned short* __restrict__ Wqkv,
    unsigned short* __restrict__ W1s, unsigned short* __restrict__ W2s) {
  int i = blockIdx.x * 256 + threadIdx.x;
  if (i < 320 * 256) {
    int r = i >> 8, c = i & 255;
    float v;
    if (r < 32)      v = Wq[r * 256 + c];
    else if (r < 64) v = Wk[(r - 32) * 256 + c];
    else             v = Wv[(r - 64) * 256 + c];
    Wqkv[i] = f2bfbits(v);
  }
  if (i < 32768) {
    int ft = i >> 9, ks = (i >> 6) & 7, l = i & 63;
    int f = ft * 16 + (l & 15), kb = ks * 32 + (l >> 4) * 8;
    #pragma unroll
    for (int j = 0; j < 8; ++j)
      W1s[i * 8 + j] = f2bfbits(W1[f * 256 + kb + j]);
  }
  if (i < 32768) {
    int ct = i >> 11, gks = (i >> 6) & 31, l = i & 63;
    int c = ct * 16 + (l & 15), fb = gks * 32 + (l >> 4) * 8;
    #pragma unroll
    for (int j = 0; j < 8; ++j)
      W2s[i * 8 + j] = f2bfbits(W2[c * 1024 + fb + j]);
  }
}

// ---------------- kernel 1: fused x-prep + QKV projection ----------------
// block = (win, mc). Stages its 64-token X quarter into LDS in fragment order
// (inline transpose+cvt of x), writes it through to Xfrag (for attn residual),
// then runs the QKV GEMM with LDS B-frags.
__global__ __launch_bounds__(256) void qkvx_kernel(
    const float* __restrict__ x, const unsigned short* __restrict__ Wqkv,
    unsigned short* __restrict__ Xfrag, unsigned short* __restrict__ Qw,
    unsigned short* __restrict__ Kw, unsigned short* __restrict__ Vw) {
  __shared__ __align__(16) short Xs[4][8][64][8];   // 32768 B, frag order

  const int bid = blockIdx.x;
  const int win = bid >> 2, mc = bid & 3;
  const int b = win >> 6, wh = (win >> 3) & 7, ww = win & 7;
  const int m0 = mc * 64;
  const int tid = threadIdx.x;
  const int wv = tid >> 6, l = tid & 63;
  const int t = l & 15, q = l >> 4;

  unsigned short* XFb = Xfrag + (size_t)win * 65536 + (size_t)mc * 16384;
  short8* XsLin = (short8*)&Xs[0][0][0][0];

  // stage: idx = (mt_l, ks, lane); 8 strided f32 loads -> one 16B frag
  #pragma unroll
  for (int rep = 0; rep < 8; ++rep) {
    const int idx = rep * 256 + tid;
    const int mt_l = idx >> 9, kss = (idx >> 6) & 7, ll = idx & 63;
    const int tt = ll & 15, qq = ll >> 4;
    const int h = wh * 16 + mc * 4 + mt_l, w = ww * 16 + tt;
    const int c0 = kss * 32 + qq * 8;
    const float* xp = x + ((size_t)(b * 256 + c0) * 128 + h) * 128 + w;
    short8 v;
    #pragma unroll
    for (int j = 0; j < 8; ++j)
      v[j] = (short)f2bfbits(xp[(size_t)j * 16384]);
    XsLin[idx] = v;
    *(short8*)(XFb + (size_t)idx * 8) = v;
  }
  __syncthreads();

  for (int mt = 0; mt < 4; ++mt) {
    short8 Bf[8];
    #pragma unroll
    for (int ks = 0; ks < 8; ++ks)
      Bf[ks] = *(const short8*)&Xs[mt][ks][l][0];
    #pragma unroll
    for (int rti = 0; rti < 5; ++rti) {
      const int rt = wv * 5 + rti;
      const int r0 = rt * 16;
      f32x4 acc = (f32x4){0.f, 0.f, 0.f, 0.f};
      #pragma unroll
      for (int ks = 0; ks < 8; ++ks) {
        short8 av = *(const short8*)(Wqkv + (size_t)(r0 + t) * 256 + ks * 32 + q * 8);
        acc = __builtin_amdgcn_mfma_f32_16x16x32_bf16(av, Bf[ks], acc, 0, 0, 0);
      }
      const int n = m0 + mt * 16 + t;   // token
      if (rt < 4) {
        ushort4 u;
        u.x = f2bfbits(acc[0]); u.y = f2bfbits(acc[1]);
        u.z = f2bfbits(acc[2]); u.w = f2bfbits(acc[3]);
        unsigned short* dst = (rt < 2) ? Qw : Kw;
        int o0 = (rt & 1) * 16 + q * 4;
        *(ushort4*)(dst + ((size_t)win * 256 + n) * 32 + o0) = u;
      } else {
        #pragma unroll
        for (int r = 0; r < 4; ++r) {
          int c = r0 - 64 + q * 4 + r;
          Vw[((size_t)win * 256 + c) * 256 + n] = f2bfbits(acc[r]);
        }
      }
    }
  }
}

// ---------------- kernel 2: fused attention + FFN + LayerNorms ----------------
// block = (win, wr): 64 tokens, 4 waves. Attn phase (double-buffered Ps, one
// barrier per mcc) -> epilogue writes XA into the Xf LDS tile (overlaying the
// dead Ps buffer; no global XA round-trip) -> FFN phase -> out (NCHW fp32).
__global__ __launch_bounds__(256, 3) void attn_ffn_kernel(
    const unsigned short* __restrict__ Qw, const unsigned short* __restrict__ Kw,
    const unsigned short* __restrict__ Vw, const unsigned short* __restrict__ Xfrag,
    const float* __restrict__ gamma,
    const unsigned short* __restrict__ W1s, const unsigned short* __restrict__ W2s,
    const float* __restrict__ b1, const float* __restrict__ b2,
    const float* __restrict__ ln1w, const float* __restrict__ ln1b,
    const float* __restrict__ ln2w, const float* __restrict__ ln2b,
    float* __restrict__ out) {
  __shared__ __align__(16) short XfPs[16384];   // 32768 B: phase1 Ps[2][64][72]+Lpart, phase2 Xf[4][8][64][8]
  __shared__ __align__(16) short Ht[64][136];   // 17408 B
  __shared__ float red[2][4][64];               // 2048 B
  __shared__ float Ls[64];                      // 256 B

  short (*Ps)[64][72] = (short(*)[64][72])&XfPs[0];          // 18432 B
  float* Lpart = (float*)&XfPs[9216];                        // byte 18432, 1024 B
  short (*Xf)[8][64][8] = (short(*)[8][64][8])&XfPs[0];      // 32768 B (phase 2)

  // bijective XCD swizzle (2048 % 8 == 0): a window's 4 blocks share an XCD
  const int bid = blockIdx.x;
  const int wgb = (bid & 7) * 256 + (bid >> 3);
  const int win = wgb >> 2, wr = wgb & 3;
  const int b = win >> 6, wh = (win >> 3) & 7, ww = win & 7;

  const int tid = threadIdx.x;
  const int wc = tid >> 6, l = tid & 63;
  const int t = l & 15, q = l >> 4;

  // ================= phase 1: attention =================
  f32x4 Oacc[4][4];   // [k: c-tile][i: n-tile]
  #pragma unroll
  for (int k = 0; k < 4; ++k)
    #pragma unroll
    for (int i = 0; i < 4; ++i)
      Oacc[k][i] = (f32x4){0.f, 0.f, 0.f, 0.f};
  float lsum[16];
  #pragma unroll
  for (int e = 0; e < 16; ++e) lsum[e] = 0.f;

  const unsigned short* Qb = Qw + (size_t)win * 256 * 32;
  const unsigned short* Kb = Kw + (size_t)win * 256 * 32;
  const unsigned short* Vb = Vw + (size_t)win * 65536;

  short8 aq[4];
  #pragma unroll
  for (int i = 0; i < 4; ++i)
    aq[i] = *(const short8*)(Qb + (size_t)((wr * 4 + i) * 16 + t) * 32 + q * 8);

  for (int mcc = 0; mcc < 4; ++mcc) {
    const int buf = mcc & 1;
    // ---- S chunk: m-tile mcc*4+wc, n-tiles wr*4+0..3 ----
    {
      const int m0s = (mcc * 4 + wc) * 16;
      short8 bk = *(const short8*)(Kb + (size_t)(m0s + t) * 32 + q * 8);
      f32x4 sv[4];
      #pragma unroll
      for (int i = 0; i < 4; ++i)
        sv[i] = __builtin_amdgcn_mfma_f32_16x16x32_bf16(aq[i], bk, (f32x4){0.f,0.f,0.f,0.f}, 0, 0, 0);
      #pragma unroll
      for (int i = 0; i < 4; ++i) {
        #pragma unroll
        for (int r = 0; r < 4; ++r) {
          float e = __expf(sv[i][r]);
          lsum[i * 4 + r] += e;
          Ps[buf][i * 16 + q * 4 + r][wc * 16 + t] = (short)f2bfbits(e);
        }
      }
    }
    __syncthreads();   // Ps[buf] ready; prev buf's PV complete everywhere
    // ---- PV chunk (swapped): O^T[c][n] += V[c, chunk] @ P^T[chunk, n] ----
    #pragma unroll
    for (int ks2 = 0; ks2 < 2; ++ks2) {
      short8 ap[4], bv[4];
      #pragma unroll
      for (int i = 0; i < 4; ++i)
        ap[i] = *(const short8*)&Ps[buf][i * 16 + t][ks2 * 32 + q * 8];
      #pragma unroll
      for (int k = 0; k < 4; ++k)
        bv[k] = *(const short8*)(Vb + (size_t)((wc * 4 + k) * 16 + t) * 256 + mcc * 64 + ks2 * 32 + q * 8);
      #pragma unroll
      for (int k = 0; k < 4; ++k)
        #pragma unroll
        for (int i = 0; i < 4; ++i)
          Oacc[k][i] = __builtin_amdgcn_mfma_f32_16x16x32_bf16(bv[k], ap[i], Oacc[k][i], 0, 0, 0);
    }
  }

  // ---- row sums ----
  #pragma unroll
  for (int mask = 1; mask < 16; mask <<= 1)
    #pragma unroll
    for (int e = 0; e < 16; ++e)
      lsum[e] += __shfl_xor(lsum[e], mask);
  __syncthreads();   // all PV reads of Ps done
  if (t == 0) {
    #pragma unroll
    for (int i = 0; i < 4; ++i)
      *(float4*)&Lpart[wc * 64 + i * 16 + q * 4] =
          make_float4(lsum[i * 4 + 0], lsum[i * 4 + 1], lsum[i * 4 + 2], lsum[i * 4 + 3]);
  }
  __syncthreads();
  if (tid < 64) {
    float s = Lpart[tid] + Lpart[64 + tid] + Lpart[128 + tid] + Lpart[192 + tid];
    Ls[tid] = gamma[0] / s;
  }
  __syncthreads();   // Ls ready; Ps/Lpart dead -> Xf may be written

  // ---- epilogue: residual from Xfrag, XA -> Xf (LDS, frag order) ----
  const unsigned short* Xres = Xfrag + (size_t)win * 65536;
  #pragma unroll
  for (int i = 0; i < 4; ++i) {
    const float ls = Ls[i * 16 + t];
    #pragma unroll
    for (int k = 0; k < 4; ++k) {
      const int ksx = wc * 2 + (k >> 1);
      const int lx = ((k & 1) * 2 + (q >> 1)) * 16 + t;
      const int jx = (q & 1) * 4;
      const size_t goff = (((size_t)(wr * 4 + i) * 8 + ksx) * 64 + lx) * 8 + jx;
      ushort4 xa4 = *(const ushort4*)(Xres + goff);
      const unsigned short* xp = (const unsigned short*)&xa4;
      ushort4 u;
      unsigned short* up = (unsigned short*)&u;
      #pragma unroll
      for (int r = 0; r < 4; ++r)
        up[r] = f2bfbits(ls * Oacc[k][i][r] + bf2f(xp[r]));
      *(ushort4*)&Xf[i][ksx][lx][jx] = u;
    }
  }
  __syncthreads();   // Xf complete

  // ================= phase 2: FFN + LNs =================
  const int p = t;   // lane row/col roles match ffn convention (p = l&15, q = l>>4)
  const int wv = wc;

  f32x4 Yacc[4][4];
  #pragma unroll
  for (int i = 0; i < 4; ++i)
    #pragma unroll
    for (int pt = 0; pt < 4; ++pt)
      Yacc[i][pt] = (f32x4){0.f, 0.f, 0.f, 0.f};

  const short8* W1s8 = (const short8*)W1s;
  const short8* W2s8 = (const short8*)W2s;

  for (int fc = 0; fc < 8; ++fc) {
    f32x4 Hacc[2][4];
    #pragma unroll
    for (int i = 0; i < 2; ++i)
      #pragma unroll
      for (int pt = 0; pt < 4; ++pt)
        Hacc[i][pt] = (f32x4){0.f, 0.f, 0.f, 0.f};
    const int f0 = (fc * 8 + wv * 2) * 8;
    #pragma unroll
    for (int ks = 0; ks < 8; ++ks) {
      short8 a0 = W1s8[(f0 + ks) * 64 + l];
      short8 a1 = W1s8[(f0 + 8 + ks) * 64 + l];
      #pragma unroll
      for (int pt = 0; pt < 4; ++pt) {
        short8 bf = *(const short8*)&Xf[pt][ks][l][0];
        Hacc[0][pt] = __builtin_amdgcn_mfma_f32_16x16x32_bf16(a0, bf, Hacc[0][pt], 0, 0, 0);
        Hacc[1][pt] = __builtin_amdgcn_mfma_f32_16x16x32_bf16(a1, bf, Hacc[1][pt], 0, 0, 0);
      }
    }
    __syncthreads();   // prev fc's Ht reads done
    // bias + GELU -> Ht (fast rcp: 1-ulp, absmax slack is ample)
    #pragma unroll
    for (int i = 0; i < 2; ++i) {
      float4 bv1 = *(const float4*)(b1 + fc * 128 + wv * 32 + i * 16 + q * 4);
      #pragma unroll
      for (int pt = 0; pt < 4; ++pt) {
        ushort4 hbv;
        unsigned short* hp = (unsigned short*)&hbv;
        #pragma unroll
        for (int r = 0; r < 4; ++r) {
          float v = Hacc[i][pt][r] + ((const float*)&bv1)[r];
          float u = 0.7978845608f * fmaf(0.044715f * v, v * v, v);
          float e = __expf(2.f * u);
          float g = v - v * __builtin_amdgcn_rcpf(e + 1.f);
          hp[r] = f2bfbits(g);
        }
        *(ushort4*)&Ht[pt * 16 + p][wv * 32 + i * 16 + q * 4] = hbv;
      }
    }
    __syncthreads();   // Ht ready
    #pragma unroll
    for (int fs = 0; fs < 4; ++fs) {
      short8 av[4];
      #pragma unroll
      for (int i = 0; i < 4; ++i)
        av[i] = W2s8[((wv * 4 + i) * 32 + fc * 4 + fs) * 64 + l];
      #pragma unroll
      for (int pt = 0; pt < 4; ++pt) {
        short8 bf = *(const short8*)&Ht[pt * 16 + p][fs * 32 + q * 8];
        #pragma unroll
        for (int i = 0; i < 4; ++i)
          Yacc[i][pt] = __builtin_amdgcn_mfma_f32_16x16x32_bf16(av[i], bf, Yacc[i][pt], 0, 0, 0);
      }
    }
  }

  // bias b2
  #pragma unroll
  for (int i = 0; i < 4; ++i) {
    float4 bb = *(const float4*)(b2 + wv * 64 + i * 16 + q * 4);
    #pragma unroll
    for (int pt = 0; pt < 4; ++pt)
      #pragma unroll
      for (int r = 0; r < 4; ++r)
        Yacc[i][pt][r] += ((const float*)&bb)[r];
  }

  // LN1 stats
  #pragma unroll
  for (int pt = 0; pt < 4; ++pt) {
    float ss = 0.f, sq = 0.f;
    #pragma unroll
    for (int i = 0; i < 4; ++i)
      #pragma unroll
      for (int r = 0; r < 4; ++r) { float v = Yacc[i][pt][r]; ss += v; sq += v * v; }
    ss += __shfl_xor(ss, 16); sq += __shfl_xor(sq, 16);
    ss += __shfl_xor(ss, 32); sq += __shfl_xor(sq, 32);
    if (l < 16) { red[0][wv][pt * 16 + l] = ss; red[1][wv][pt * 16 + l] = sq; }
  }
  __syncthreads();
  if (tid < 64) {
    float S  = red[0][0][tid] + red[0][1][tid] + red[0][2][tid] + red[0][3][tid];
    float Q2 = red[1][0][tid] + red[1][1][tid] + red[1][2][tid] + red[1][3][tid];
    float m = S * 0.00390625f;
    float va = Q2 * 0.00390625f - m * m;
    red[0][0][tid] = m; red[1][0][tid] = rsqrtf(va + 1e-5f);
  }
  __syncthreads();
  // x2 = xa + LN1(y); xa from Xf (LDS)
  #pragma unroll
  for (int i = 0; i < 4; ++i) {
    float4 w1v = *(const float4*)(ln1w + wv * 64 + i * 16 + q * 4);
    float4 b1v = *(const float4*)(ln1b + wv * 64 + i * 16 + q * 4);
    const int ksx = wv * 2 + (i >> 1);
    const int lq = (i & 1) * 2 + (q >> 1);
    #pragma unroll
    for (int pt = 0; pt < 4; ++pt) {
      int px = pt * 16 + p;
      float mu = red[0][0][px], rs = red[1][0][px];
      ushort4 xa4 = *(const ushort4*)&Xf[pt][ksx][lq * 16 + p][(q & 1) * 4];
      const unsigned short* xp = (const unsigned short*)&xa4;
      #pragma unroll
      for (int r = 0; r < 4; ++r)
        Yacc[i][pt][r] = bf2f(xp[r]) + (Yacc[i][pt][r] - mu) * rs * ((const float*)&w1v)[r] + ((const float*)&b1v)[r];
    }
  }
  __syncthreads();
  // LN2 stats
  #pragma unroll
  for (int pt = 0; pt < 4; ++pt) {
    float ss = 0.f, sq = 0.f;
    #pragma unroll
    for (int i = 0; i < 4; ++i)
      #pragma unroll
      for (int r = 0; r < 4; ++r) { float v = Yacc[i][pt][r]; ss += v; sq += v * v; }
    ss += __shfl_xor(ss, 16); sq += __shfl_xor(sq, 16);
    ss += __shfl_xor(ss, 32); sq += __shfl_xor(sq, 32);
    if (l < 16) { red[0][wv][pt * 16 + l] = ss; red[1][wv][pt * 16 + l] = sq; }
  }
  __syncthreads();
  if (tid < 64) {
    float S  = red[0][0][tid] + red[0][1][tid] + red[0][2][tid] + red[0][3][tid];
    float Q2 = red[1][0][tid] + red[1][1][tid] + red[1][2][tid] + red[1][3][tid];
    float m = S * 0.00390625f;
    float va = Q2 * 0.00390625f - m * m;
    red[0][0][tid] = m; red[1][0][tid] = rsqrtf(va + 1e-5f);
  }
  __syncthreads();
  // out = x2 + LN2(x2), NCHW
  #pragma unroll
  for (int i = 0; i < 4; ++i) {
    float4 w2v = *(const float4*)(ln2w + wv * 64 + i * 16 + q * 4);
    float4 b2v = *(const float4*)(ln2b + wv * 64 + i * 16 + q * 4);
    #pragma unroll
    for (int pt = 0; pt < 4; ++pt) {
      int px = pt * 16 + p;
      float mu = red[0][0][px], rs = red[1][0][px];
      #pragma unroll
      for (int r = 0; r < 4; ++r) {
        int c = wv * 64 + i * 16 + q * 4 + r;
        float x2 = Yacc[i][pt][r];
        float o = x2 + (x2 - mu) * rs * ((const float*)&w2v)[r] + ((const float*)&b2v)[r];
        out[(((size_t)(b * 256 + c) * 128) + wh * 16 + wr * 4 + pt) * 128 + ww * 16 + p] = o;
      }
    }
  }
}

extern "C" void kernel_launch(void* const* d_in, const int* in_sizes, int n_in,
                              void* d_out, int out_size, void* d_ws, size_t ws_size,
                              hipStream_t stream) {
  const float* x     = (const float*)d_in[0];
  const float* Wq    = (const float*)d_in[1];
  const float* Wk    = (const float*)d_in[2];
  const float* Wv    = (const float*)d_in[3];
  const float* gamma = (const float*)d_in[4];
  const float* W1    = (const float*)d_in[5];
  const float* b1    = (const float*)d_in[6];
  const float* W2    = (const float*)d_in[7];
  const float* b2    = (const float*)d_in[8];
  const float* ln1w  = (const float*)d_in[9];
  const float* ln1b  = (const float*)d_in[10];
  const float* ln2w  = (const float*)d_in[11];
  const float* ln2b  = (const float*)d_in[12];
  float* out = (float*)d_out;

  char* wsb = (char*)d_ws;
  unsigned short* Xfrag = (unsigned short*)wsb;                 // 67108864 B, frag order
  unsigned short* Vw    = (unsigned short*)(wsb + 67108864);    // 67108864 B
  unsigned short* Qw    = (unsigned short*)(wsb + 134217728);   // 8388608 B
  unsigned short* Kw    = (unsigned short*)(wsb + 142606336);   // 8388608 B
  unsigned short* Wqkv  = (unsigned short*)(wsb + 150994944);   // 163840 B
  unsigned short* W1s   = (unsigned short*)(wsb + 151158784);   // 524288 B
  unsigned short* W2s   = (unsigned short*)(wsb + 151683072);   // 524288 B -> end ~145 MB

  prep_weights<<<1024, 256, 0, stream>>>(Wq, Wk, Wv, W1, W2, Wqkv, W1s, W2s);
  qkvx_kernel<<<2048, 256, 0, stream>>>(x, Wqkv, Xfrag, Qw, Kw, Vw);
  attn_ffn_kernel<<<2048, 256, 0, stream>>>(Qw, Kw, Vw, Xfrag, gamma,
                                            W1s, W2s, b1, b2, ln1w, ln1b, ln2w, ln2b, out);
}